// Round 2
// baseline (356.057 us; speedup 1.0000x reference)
//
#include <hip/hip_runtime.h>
#include <hip/hip_cooperative_groups.h>

namespace cg = cooperative_groups;

// NonMaxSuppression: 3x3 local max + thr>=0.6 + 10px border -> ordered (y,x) coords.
// Input fixed: (16,1,1536,1536) fp32.
// SINGLE cooperative kernel. Each block owns a 48-row strip (512 blocks x 384 threads,
// exactly 2 blocks/CU co-resident; __launch_bounds__(384,3) guarantees VGPR<=170).
// Phase A: rolling-register NMS (two dword-aligned float4 loads/row -> 6-wide halo,
//          separable v_max3), u64 chunk masks kept in LDS, per-block count -> global.
// grid.sync()
// Phase B: exclusive block offset from the 512 counts (1-2 loads/thread + reduce),
//          then in-LDS mask replay + ordered (y,x) scatter. Masks never touch HBM.
#define W 1536
#define H 1536
#define NB 16
#define NROWS (NB * H)        // 24576
#define SH 48                 // rows per block strip
#define NBLK (NROWS / SH)     // 512  (= 2 blocks/CU on 256 CUs)
#define BLOCK 384             // 1536/4 cols per thread
#define CPR 24                // u64 chunks per row
#define CHUNKS (SH * CPR)     // 1152 chunks per strip
#define CPT (CHUNKS / BLOCK)  // 3 chunks per thread in phase B
#define REP_THR 0.6f

__device__ __forceinline__ float max3f(float a, float b, float c) {
    return fmaxf(fmaxf(a, b), c);  // v_max3_f32
}

__device__ __forceinline__ float4 ld4u(const float* p) {
    float4 r;
    __builtin_memcpy(&r, p, 16);
    return r;
}

__global__ __launch_bounds__(BLOCK, 3) void nms_fused(const float* __restrict__ in,
                                                      unsigned int* __restrict__ counts,
                                                      int* __restrict__ out,
                                                      unsigned int K) {
    __shared__ unsigned long long lmask[CHUNKS];   // 9216 B
    __shared__ unsigned wred[BLOCK / 64];
    __shared__ unsigned sred[BLOCK / 64];

    const int t = threadIdx.x;
    const int lane = t & 63;
    const int wv = t >> 6;
    const int blk = blockIdx.x;
    const int r0 = blk * SH;                 // first output row (global)
    const int ytile = blk % (H / SH);        // strip index within image

    // column windows: va covers cols 4t-1..4t+2, vb covers 4t+1..4t+4 (clamped at edges;
    // clamped lanes produce garbage only where the x-border mask kills the result)
    const int ca = (t == 0) ? 0 : 4 * t - 1;
    const int cb = (t == BLOCK - 1) ? 4 * t : 4 * t + 1;

    // x-border nibble mask, valid x in [10, 1526)
    unsigned colm = 0xFu;
    if (t <= 1) colm = 0u;
    else if (t == 2) colm = 0xCu;
    if (t >= 382) colm = 0u;
    else if (t == 381) colm = 0x3u;

    auto rowp = [&](int i) {                 // input row rel i (rel 0 = r0-1), clamped
        int ir = r0 - 1 + i;
        ir = ir < 0 ? 0 : (ir >= NROWS ? NROWS - 1 : ir);
        return in + (size_t)ir * W;
    };

    // ---------- Phase A: NMS into LDS masks ----------
    float4 va0 = ld4u(rowp(0) + ca), vb0 = ld4u(rowp(0) + cb);
    float4 va1 = ld4u(rowp(1) + ca), vb1 = ld4u(rowp(1) + cb);
    float4 vaN = ld4u(rowp(2) + ca), vbN = ld4u(rowp(2) + cb);

    float4 hA, hB, ctrB;
    hA.x = max3f(va0.x, va0.y, va0.z);
    hA.y = max3f(va0.y, va0.z, va0.w);
    hA.z = max3f(vb0.x, vb0.y, vb0.z);
    hA.w = max3f(vb0.y, vb0.z, vb0.w);
    hB.x = max3f(va1.x, va1.y, va1.z);
    hB.y = max3f(va1.y, va1.z, va1.w);
    hB.z = max3f(vb1.x, vb1.y, vb1.z);
    hB.w = max3f(vb1.y, vb1.z, vb1.w);
    ctrB.x = va1.y; ctrB.y = va1.z; ctrB.z = va1.w; ctrB.w = vb1.z;

    unsigned cnt = 0;
#pragma unroll 8
    for (int i = 2; i <= SH + 1; ++i) {
        float4 va = vaN, vb = vbN;
        vaN = ld4u(rowp(i + 1) + ca);        // depth-1 prefetch (clamped; overshoot harmless)
        vbN = ld4u(rowp(i + 1) + cb);
        float4 hC;
        hC.x = max3f(va.x, va.y, va.z);
        hC.y = max3f(va.y, va.z, va.w);
        hC.z = max3f(vb.x, vb.y, vb.z);
        hC.w = max3f(vb.y, vb.z, vb.w);

        const int yloc = ytile * SH + (i - 2);   // image-local y of emitted row
        unsigned nib = 0u;
        if (yloc >= 10 && yloc < H - 10) {
            nib |= (ctrB.x >= fmaxf(max3f(hA.x, hB.x, hC.x), REP_THR)) ? 1u : 0u;
            nib |= (ctrB.y >= fmaxf(max3f(hA.y, hB.y, hC.y), REP_THR)) ? 2u : 0u;
            nib |= (ctrB.z >= fmaxf(max3f(hA.z, hB.z, hC.z), REP_THR)) ? 4u : 0u;
            nib |= (ctrB.w >= fmaxf(max3f(hA.w, hB.w, hC.w), REP_THR)) ? 8u : 0u;
            nib &= colm;
        }
        cnt += __popc(nib);
        // fold 16 lanes' nibbles -> u64 chunk (lane%16==0 stores to LDS)
        unsigned x = nib;
        x |= __shfl_down(x, 1, 64) << 4;
        x |= __shfl_down(x, 2, 64) << 8;
        x |= __shfl_down(x, 4, 64) << 16;
        unsigned hi = __shfl_down(x, 8, 64);
        if ((lane & 15) == 0) {
            unsigned long long m64 = (unsigned long long)x | ((unsigned long long)hi << 32);
            lmask[(i - 2) * CPR + (t >> 4)] = m64;
        }
        hA = hB; hB = hC;
        ctrB.x = va.y; ctrB.y = va.z; ctrB.z = va.w; ctrB.w = vb.z;
    }

    // per-block count -> global (agent-scope release; grid sync orders readers)
#pragma unroll
    for (int o = 32; o > 0; o >>= 1) cnt += __shfl_down(cnt, o, 64);
    if (lane == 0) wred[wv] = cnt;
    __syncthreads();
    if (t == 0) {
        unsigned s = 0;
#pragma unroll
        for (int k = 0; k < BLOCK / 64; ++k) s += wred[k];
        __hip_atomic_store(&counts[blk], s, __ATOMIC_RELEASE, __HIP_MEMORY_SCOPE_AGENT);
    }

    cg::this_grid().sync();

    // ---------- Phase B: offsets + ordered scatter ----------
    unsigned long long b[CPT];
    unsigned c[CPT];
    unsigned cnt2 = 0;
#pragma unroll
    for (int k = 0; k < CPT; ++k) {
        b[k] = lmask[t * CPT + k];
        c[k] = (unsigned)__popcll(b[k]);
        cnt2 += c[k];
    }
    unsigned incl = cnt2;
#pragma unroll
    for (int o = 1; o < 64; o <<= 1) {
        unsigned u = __shfl_up(incl, o, 64);
        if (lane >= o) incl += u;
    }
    // exclusive block offset: sum of counts[0..blk), <=2 loads/thread (NBLK=512)
    unsigned part = 0;
    if (t < blk) part += __hip_atomic_load(&counts[t], __ATOMIC_ACQUIRE, __HIP_MEMORY_SCOPE_AGENT);
    if (t + BLOCK < blk) part += __hip_atomic_load(&counts[t + BLOCK], __ATOMIC_ACQUIRE, __HIP_MEMORY_SCOPE_AGENT);
#pragma unroll
    for (int o = 32; o > 0; o >>= 1) part += __shfl_down(part, o, 64);
    if (lane == 63) wred[wv] = incl;   // safe: grid.sync() separated phase-A use
    if (lane == 0) sred[wv] = part;
    __syncthreads();
    unsigned pos = incl - cnt2;
#pragma unroll
    for (int k = 0; k < BLOCK / 64; ++k) {
        pos += sred[k];
        if (k < wv) pos += wred[k];
    }
    // ordered replay: thread t owns chunks 3t..3t+2 (row-major => spatial order)
#pragma unroll
    for (int k = 0; k < CPT; ++k) {
        unsigned long long bits = b[k];
        if (bits) {
            const int cidx = t * CPT + k;
            const int y = ytile * SH + cidx / CPR;   // image-local row
            const int x0 = (cidx % CPR) * 64;
            while (bits) {
                int j = __builtin_ctzll(bits);
                bits &= bits - 1ull;
                if (pos < K) { out[pos] = y; out[K + pos] = x0 + j; }
                ++pos;
            }
        }
    }
}

extern "C" void kernel_launch(void* const* d_in, const int* in_sizes, int n_in,
                              void* d_out, int out_size, void* d_ws, size_t ws_size,
                              hipStream_t stream) {
    const float* in = (const float*)d_in[0];
    int* out = (int*)d_out;
    unsigned int* counts = (unsigned int*)d_ws;   // 512 u32
    unsigned int K = (unsigned int)(out_size / 2);

    void* args[] = {(void*)&in, (void*)&counts, (void*)&out, (void*)&K};
    hipLaunchCooperativeKernel((void*)nms_fused, dim3(NBLK), dim3(BLOCK), args, 0, stream);
}

// Round 3
// 234.781 us; speedup vs baseline: 1.5165x; 1.5165x over previous
//
#include <hip/hip_runtime.h>

// NonMaxSuppression: 3x3 local max + thr>=0.6 + 10px border -> ordered (y,x) coords.
// Input fixed: (16,1,1536,1536) fp32.
// Pass1: barrier-free rolling-register NMS. 1536 blocks x 384 threads; block = 16 rows,
//        thread = 4 aligned cols. ONE aligned float4/row + 2 wave shuffles for the 6-wide
//        halo (predicated scalar at wave edges); separable v_max3 vertical window rolls
//        in registers. u64 masks + per-block counts to global.
// Pass2 (fused scan+scatter): 768 blocks x 768 threads (32-row strips). Block offset from
//        the 1536 counts (2 loads/thread + reduce). Replay masks into LDS as packed
//        (y|x<<16), then COALESCED write of both output streams. Direct-scatter fallback
//        past CAP keeps arbitrary inputs correct.
#define W 1536
#define H 1536
#define NB 16
#define NROWS (NB * H)          // 24576
#define SH1 16                  // rows per pass1 block
#define NBLK1 (NROWS / SH1)     // 1536
#define BLOCK1 384              // 1536/4 cols per thread
#define CPR 24                  // u64 chunks per row
#define NMASK (NROWS * CPR)     // 589824 u64 = 4.72 MB
#define SH2 32                  // rows per scatter block
#define NBLK2 (NROWS / SH2)     // 768
#define BLOCK2 (SH2 * CPR)      // 768 threads
#define CAP 6144                // staged items/block (24 KB LDS); expected ~2150
#define REP_THR 0.6f

__device__ __forceinline__ float max3f(float a, float b, float c) {
    return fmaxf(fmaxf(a, b), c);  // v_max3_f32
}

__global__ __launch_bounds__(BLOCK1) void nms_pass1(const float* __restrict__ in,
                                                    unsigned long long* __restrict__ masks,
                                                    unsigned int* __restrict__ counts) {
    const int t = threadIdx.x;
    const int lane = t & 63;
    const int wv = t >> 6;
    const int blk = blockIdx.x;
    const int r0 = blk * SH1;                // first output row (global)
    const int ytile = blk % (H / SH1);       // strip index within image

    const int c0 = 4 * t;                    // aligned float4 column base
    // wave-edge halo columns (clamped; clamped lanes masked by colm)
    const int cl = (t == 0) ? 0 : c0 - 1;
    const int cr = (t == BLOCK1 - 1) ? (W - 1) : c0 + 4;

    // x-border nibble mask, valid x in [10, 1526); bit j <-> col 4t+j
    unsigned colm = 0xFu;
    if (t <= 1) colm = 0u;
    else if (t == 2) colm = 0xCu;
    if (t >= 382) colm = 0u;
    else if (t == 381) colm = 0x3u;

    auto rowp = [&](int i) {                 // input row rel i (rel 0 = r0-1), clamped
        int ir = r0 - 1 + i;
        ir = ir < 0 ? 0 : (ir >= NROWS ? NROWS - 1 : ir);
        return in + (size_t)ir * W;
    };

    // halo via wave shuffle: h[j] = max of cols c0+j-1 .. c0+j+1
    auto mkhalo = [&](float4 v, float lw, float rx) {
        float lw_all = __shfl_up(v.w, 1, 64);
        if (lane == 0) lw_all = lw;          // from predicated edge load
        float rx_all = __shfl_down(v.x, 1, 64);
        if (lane == 63) rx_all = rx;
        float4 h;
        h.x = max3f(lw_all, v.x, v.y);
        h.y = max3f(v.x, v.y, v.z);
        h.z = max3f(v.y, v.z, v.w);
        h.w = max3f(v.z, v.w, rx_all);
        return h;
    };

    // prologue: rows rel 0,1 and prefetch rel 2
    float4 v0 = *(const float4*)(rowp(0) + c0);
    float lw0 = 0.f, rx0 = 0.f;
    if (lane == 0) lw0 = rowp(0)[cl];
    if (lane == 63) rx0 = rowp(0)[cr];
    float4 v1 = *(const float4*)(rowp(1) + c0);
    float lw1 = 0.f, rx1 = 0.f;
    if (lane == 0) lw1 = rowp(1)[cl];
    if (lane == 63) rx1 = rowp(1)[cr];
    float4 vN = *(const float4*)(rowp(2) + c0);
    float lwN = 0.f, rxN = 0.f;
    if (lane == 0) lwN = rowp(2)[cl];
    if (lane == 63) rxN = rowp(2)[cr];

    float4 hA = mkhalo(v0, lw0, rx0);
    float4 hB = mkhalo(v1, lw1, rx1);
    float4 ctrB = v1;                        // center row values (cols c0..c0+3)

    unsigned cnt = 0;
#pragma unroll
    for (int i = 2; i <= SH1 + 1; ++i) {
        float4 v = vN;
        float lwc = lwN, rxc = rxN;
        vN = *(const float4*)(rowp(i + 1) + c0);   // depth-1 prefetch (clamped)
        lwN = 0.f; rxN = 0.f;
        if (lane == 0) lwN = rowp(i + 1)[cl];
        if (lane == 63) rxN = rowp(i + 1)[cr];

        float4 hC = mkhalo(v, lwc, rxc);

        const int yloc = ytile * SH1 + (i - 2);    // image-local y of emitted row
        unsigned nib = 0u;
        if (yloc >= 10 && yloc < H - 10) {
            nib |= (ctrB.x >= fmaxf(max3f(hA.x, hB.x, hC.x), REP_THR)) ? 1u : 0u;
            nib |= (ctrB.y >= fmaxf(max3f(hA.y, hB.y, hC.y), REP_THR)) ? 2u : 0u;
            nib |= (ctrB.z >= fmaxf(max3f(hA.z, hB.z, hC.z), REP_THR)) ? 4u : 0u;
            nib |= (ctrB.w >= fmaxf(max3f(hA.w, hB.w, hC.w), REP_THR)) ? 8u : 0u;
            nib &= colm;
        }
        cnt += __popc(nib);
        // fold 16 lanes' nibbles -> u64 chunk (lane%16==0 stores)
        unsigned x = nib;
        x |= __shfl_down(x, 1, 64) << 4;
        x |= __shfl_down(x, 2, 64) << 8;
        x |= __shfl_down(x, 4, 64) << 16;
        unsigned hi = __shfl_down(x, 8, 64);
        if ((lane & 15) == 0) {
            unsigned long long m64 = (unsigned long long)x | ((unsigned long long)hi << 32);
            masks[(size_t)(r0 + i - 2) * CPR + (t >> 4)] = m64;
        }
        hA = hB; hB = hC; ctrB = v;
    }

#pragma unroll
    for (int o = 32; o > 0; o >>= 1) cnt += __shfl_down(cnt, o, 64);
    __shared__ unsigned wsum[BLOCK1 / 64];
    if (lane == 0) wsum[wv] = cnt;
    __syncthreads();
    if (t == 0) {
        unsigned s = 0;
#pragma unroll
        for (int k = 0; k < BLOCK1 / 64; ++k) s += wsum[k];
        counts[blk] = s;
    }
}

// Pass 2: fused scan + scatter with LDS-staged coalesced output.
// One u64 chunk per thread (row-major => thread order == spatial order).
__global__ __launch_bounds__(BLOCK2) void nms_scatter(const unsigned long long* __restrict__ masks,
                                                      const unsigned int* __restrict__ counts,
                                                      int* __restrict__ out, unsigned int K) {
    __shared__ unsigned wtot[BLOCK2 / 64];
    __shared__ unsigned sred[BLOCK2 / 64];
    __shared__ unsigned pk[CAP];             // packed y | x<<16
    const int t = threadIdx.x, lane = t & 63, wv = t >> 6;
    const int blk = blockIdx.x;
    unsigned long long bits = masks[(size_t)blk * BLOCK2 + t];
    const unsigned cnt = (unsigned)__popcll(bits);
    unsigned incl = cnt;
#pragma unroll
    for (int o = 1; o < 64; o <<= 1) {
        unsigned u = __shfl_up(incl, o, 64);
        if (lane >= o) incl += u;
    }
    // exclusive block offset: sum of counts[0..2*blk) over 1536 pass1 counts
    unsigned part = 0;
    if (t < 2 * blk) part += counts[t];
    if (t + BLOCK2 < 2 * blk) part += counts[t + BLOCK2];
#pragma unroll
    for (int o = 32; o > 0; o >>= 1) part += __shfl_down(part, o, 64);
    if (lane == 63) wtot[wv] = incl;
    if (lane == 0) sred[wv] = part;
    __syncthreads();
    unsigned blockBase = 0, blockCnt = 0, wbase = 0;
#pragma unroll
    for (int k = 0; k < BLOCK2 / 64; ++k) {
        blockBase += sred[k];
        blockCnt += wtot[k];
        if (k < wv) wbase += wtot[k];
    }
    unsigned local = wbase + (incl - cnt);   // block-local index of this thread's first item
    if (bits) {
        const int y = (blk % (H / SH2)) * SH2 + t / CPR;   // image-local row
        const int x0 = (t % CPR) * 64;
        while (bits) {
            int j = __builtin_ctzll(bits);
            bits &= bits - 1ull;
            if (local < CAP) {
                pk[local] = (unsigned)y | ((unsigned)(x0 + j) << 16);
            } else {                          // overflow fallback (correct for any input)
                unsigned g = blockBase + local;
                if (g < K) { out[g] = y; out[K + g] = x0 + j; }
            }
            ++local;
        }
    }
    __syncthreads();
    const unsigned lim = blockCnt < CAP ? blockCnt : CAP;
    for (unsigned i = t; i < lim; i += BLOCK2) {
        unsigned g = blockBase + i;
        if (g < K) {
            unsigned p = pk[i];
            out[g] = (int)(p & 0xFFFFu);
            out[K + g] = (int)(p >> 16);
        }
    }
}

extern "C" void kernel_launch(void* const* d_in, const int* in_sizes, int n_in,
                              void* d_out, int out_size, void* d_ws, size_t ws_size,
                              hipStream_t stream) {
    const float* in = (const float*)d_in[0];
    int* out = (int*)d_out;
    unsigned long long* masks = (unsigned long long*)d_ws;
    unsigned int* counts = (unsigned int*)((char*)d_ws + (size_t)NMASK * 8);
    const unsigned K = (unsigned)(out_size / 2);

    nms_pass1<<<NBLK1, BLOCK1, 0, stream>>>(in, masks, counts);
    nms_scatter<<<NBLK2, BLOCK2, 0, stream>>>(masks, counts, out, K);
}